// Round 3
// baseline (583.064 us; speedup 1.0000x reference)
//
#include <hip/hip_runtime.h>

// ---------------------------------------------------------------------------
// GAT (2-layer) on MI355X. All float tensors are FP32 (per reference);
// adj is int32. N = 8192 nodes, D = 64.
//   k_prep : Wh = x@W^T+b (fp32), writes WhT (bf16, 64x8192) + s,d vectors.
//            mode0: x = concat(user_emb,item_emb); mode1: x = relu(num/den).
//   k_agg  : masked-softmax aggregation via MFMA 16x16x32 bf16.
//            w = exp(leaky_relu(s_i+d_j)) (no max-subtraction needed: |s+d|<1).
//            K split 8-way across blocks; fp32 atomicAdd into num/den.
//            Denominator via 5th MFMA against an all-ones B fragment.
//   k_out  : out = relu(num/den) @ out_w^T + out_b -> d_out (fp32)
// Workspace: ~6.4 MB.
// ---------------------------------------------------------------------------

typedef __attribute__((ext_vector_type(8))) __bf16 bf16x8;
typedef __attribute__((ext_vector_type(4))) float  f32x4;

union Frag {
    bf16x8         v;
    unsigned int   w[4];
    unsigned short h[8];
};

__device__ __forceinline__ unsigned short f2bf(float f) {
    unsigned int u = __float_as_uint(f);
    u += 0x7FFFu + ((u >> 16) & 1u);          // round-to-nearest-even
    return (unsigned short)(u >> 16);
}

// ------------------------------- prep --------------------------------------
// 64 rows per block, 256 threads. fp32 GEMM x@W^T+b via LDS; emits bf16 WhT
// (transposed: WhT[o][node]) and per-node attention scalars s,d.
__global__ __launch_bounds__(256) void k_prep(
    const float* __restrict__ ue, const float* __restrict__ ie,
    const float* __restrict__ num, const float* __restrict__ den, int mode,
    const float* __restrict__ W, const float* __restrict__ bias,
    const float* __restrict__ avec,
    unsigned short* __restrict__ WhT,
    float* __restrict__ sraw, float* __restrict__ draw)
{
    __shared__ float xs[64][65];
    __shared__ float Wt[64][65];
    __shared__ float sred[4][64];
    __shared__ float dred[4][64];

    int tid = threadIdx.x;
    int r0  = blockIdx.x * 64;

    for (int e = tid; e < 4096; e += 256) {
        int r = e >> 6, c = e & 63;
        int row = r0 + r;
        float v;
        if (mode) {
            float dd = fmaxf(den[row], 1e-20f);
            v = num[row * 64 + c] / dd;
            v = v > 0.f ? v : 0.f;                 // relu between layers
        } else {
            v = (row < 4096) ? ue[row * 64 + c] : ie[(row - 4096) * 64 + c];
        }
        xs[r][c] = v;
    }
    for (int e = tid; e < 4096; e += 256) {
        int o = e >> 6, c = e & 63;
        Wt[c][o] = W[e];               // W row-major [o][c] -> transposed LDS
    }
    __syncthreads();

    int r = tid & 63, chunk = tid >> 6, c0 = chunk * 16;
    float acc[16];
#pragma unroll
    for (int o = 0; o < 16; o++) acc[o] = bias[c0 + o];
    for (int c = 0; c < 64; c++) {
        float xv = xs[r][c];
#pragma unroll
        for (int o = 0; o < 16; o++) acc[o] += xv * Wt[c][c0 + o];
    }

    float sp = 0.f, dp = 0.f;
#pragma unroll
    for (int o = 0; o < 16; o++) {
        sp += acc[o] * avec[c0 + o];          // a[:64]
        dp += acc[o] * avec[64 + c0 + o];     // a[64:]
    }
    sred[chunk][r] = sp;
    dred[chunk][r] = dp;

    // WhT[o][node]: the wave's 64 lanes hit 64 consecutive nodes per store
#pragma unroll
    for (int o = 0; o < 16; o++)
        WhT[(c0 + o) * 8192 + r0 + r] = f2bf(acc[o]);

    __syncthreads();
    if (tid < 64) {
        int g = r0 + tid;
        sraw[g] = sred[0][tid] + sred[1][tid] + sred[2][tid] + sred[3][tid];
        draw[g] = dred[0][tid] + dred[1][tid] + dred[2][tid] + dred[3][tid];
    }
}

// --------------------------- aggregation (core) ----------------------------
// grid (128, 8): blockIdx.x = 64-row block, blockIdx.y = K-split (1024 cols).
// 4 waves/block; each wave computes a 16-row tile via mfma 16x16x32 bf16.
// A-frag: lane(l16,quad) holds A[m=l16][k=quad*8+j].
// B-frag: lane(l16,quad) holds B[k=quad*8+j][n=l16].
// C/D:    lane(l16,quad) holds D[row=quad*4+reg][col=l16].
__global__ __launch_bounds__(256) void k_agg(
    const int* __restrict__ adj, const unsigned short* __restrict__ WhT,
    const float* __restrict__ sraw, const float* __restrict__ draw,
    float* __restrict__ num, float* __restrict__ den)
{
    int tid  = threadIdx.x;
    int wave = tid >> 6, lane = tid & 63;
    int quad = lane >> 4, l16 = lane & 15;
    int rowblk = blockIdx.x, ks = blockIdx.y;
    int row = rowblk * 64 + wave * 16 + l16;
    const int KR = 1024;
    int k0 = ks * KR;

    float sv = sraw[row];

    f32x4 accs[4];
    f32x4 accd = {0.f, 0.f, 0.f, 0.f};
#pragma unroll
    for (int nt = 0; nt < 4; nt++) accs[nt] = accd;

    Frag ones;
    ones.w[0] = ones.w[1] = ones.w[2] = ones.w[3] = 0x3F803F80u;  // bf16 1.0

    for (int kb = k0; kb < k0 + KR; kb += 32) {
        int kq = kb + quad * 8;                       // this lane's 8 k's

        const int4* ap = reinterpret_cast<const int4*>(adj + (size_t)row * 8192 + kq);
        int4 a0 = ap[0], a1 = ap[1];
        int ai[8] = {a0.x, a0.y, a0.z, a0.w, a1.x, a1.y, a1.z, a1.w};

        float4 dd0 = *reinterpret_cast<const float4*>(draw + kq);
        float4 dd1 = *reinterpret_cast<const float4*>(draw + kq + 4);
        float dv[8] = {dd0.x, dd0.y, dd0.z, dd0.w, dd1.x, dd1.y, dd1.z, dd1.w};

        Frag A;
#pragma unroll
        for (int j = 0; j < 8; j++) {
            float t  = sv + dv[j];
            float lr = t > 0.f ? t : 0.2f * t;        // leaky_relu, alpha=0.2
            float w  = (ai[j] != 0) ? __expf(lr) : 0.f;
            A.h[j] = f2bf(w);
        }

#pragma unroll
        for (int nt = 0; nt < 4; nt++) {
            Frag B;
            B.v = *reinterpret_cast<const bf16x8*>(WhT + (size_t)(nt * 16 + l16) * 8192 + kq);
            accs[nt] = __builtin_amdgcn_mfma_f32_16x16x32_bf16(A.v, B.v, accs[nt], 0, 0, 0);
        }
        accd = __builtin_amdgcn_mfma_f32_16x16x32_bf16(A.v, ones.v, accd, 0, 0, 0);
    }

    int rbase = rowblk * 64 + wave * 16 + quad * 4;
#pragma unroll
    for (int rr = 0; rr < 4; rr++) {
        if (l16 == 0) atomicAdd(den + rbase + rr, accd[rr]);
#pragma unroll
        for (int nt = 0; nt < 4; nt++)
            atomicAdd(num + (size_t)(rbase + rr) * 64 + nt * 16 + l16, accs[nt][rr]);
    }
}

// ----------------------------- output GEMM ---------------------------------
__global__ __launch_bounds__(256) void k_out(
    const float* __restrict__ num, const float* __restrict__ den,
    const float* __restrict__ W, const float* __restrict__ bias,
    float* __restrict__ out)
{
    __shared__ float xs[64][65];
    __shared__ float Wt[64][65];
    int tid = threadIdx.x;
    int r0  = blockIdx.x * 64;

    for (int e = tid; e < 4096; e += 256) {
        int r = e >> 6, c = e & 63;
        float dd = fmaxf(den[r0 + r], 1e-20f);
        float v = num[(r0 + r) * 64 + c] / dd;
        xs[r][c] = v > 0.f ? v : 0.f;
    }
    for (int e = tid; e < 4096; e += 256) {
        int o = e >> 6, c = e & 63;
        Wt[c][o] = W[e];
    }
    __syncthreads();

    int r = tid & 63, chunk = tid >> 6, c0 = chunk * 16;
    float acc[16];
#pragma unroll
    for (int o = 0; o < 16; o++) acc[o] = bias[c0 + o];
    for (int c = 0; c < 64; c++) {
        float xv = xs[r][c];
#pragma unroll
        for (int o = 0; o < 16; o++) acc[o] += xv * Wt[c][c0 + o];
    }
#pragma unroll
    for (int o = 0; o < 16; o++)
        out[(r0 + r) * 64 + c0 + o] = acc[o];
}

// ------------------------------- launch ------------------------------------
extern "C" void kernel_launch(void* const* d_in, const int* in_sizes, int n_in,
                              void* d_out, int out_size, void* d_ws, size_t ws_size,
                              hipStream_t stream)
{
    const int*   adj = (const int*)d_in[0];
    const float* ue  = (const float*)d_in[1];
    const float* ie  = (const float*)d_in[2];
    const float* W0w = (const float*)d_in[3];
    const float* W0b = (const float*)d_in[4];
    const float* a0  = (const float*)d_in[5];
    const float* W1w = (const float*)d_in[6];
    const float* W1b = (const float*)d_in[7];
    const float* a1  = (const float*)d_in[8];
    const float* Ow  = (const float*)d_in[9];
    const float* Ob  = (const float*)d_in[10];

    char* ws = (char*)d_ws;
    size_t off = 0;
    auto alloc = [&](size_t bytes) -> char* {
        char* p = ws + off;
        off += (bytes + 255) & ~(size_t)255;
        return p;
    };
    unsigned short* WhT0 = (unsigned short*)alloc(64 * 8192 * 2);   // 1 MB
    unsigned short* WhT1 = (unsigned short*)alloc(64 * 8192 * 2);   // 1 MB
    float* sr0  = (float*)alloc(8192 * 4);
    float* dr0  = (float*)alloc(8192 * 4);
    float* sr1  = (float*)alloc(8192 * 4);
    float* dr1  = (float*)alloc(8192 * 4);
    float* num0 = (float*)alloc(8192 * 64 * 4);                     // 2 MB
    float* den0 = (float*)alloc(8192 * 4);                          // follows num0
    float* num1 = (float*)alloc(8192 * 64 * 4);
    float* den1 = (float*)alloc(8192 * 4);
    // total ~6.4 MB

    // zero the atomic accumulators (ws is poisoned 0xAA before every launch)
    hipMemsetAsync(num0, 0, (8192 * 64 + 8192) * 4, stream);
    hipMemsetAsync(num1, 0, (8192 * 64 + 8192) * 4, stream);

    // layer 0
    k_prep<<<128, 256, 0, stream>>>(ue, ie, (const float*)nullptr, (const float*)nullptr, 0,
                                    W0w, W0b, a0, WhT0, sr0, dr0);
    k_agg<<<dim3(128, 8), 256, 0, stream>>>(adj, WhT0, sr0, dr0, num0, den0);
    // layer 1
    k_prep<<<128, 256, 0, stream>>>(ue, ie, num0, den0, 1,
                                    W1w, W1b, a1, WhT1, sr1, dr1);
    k_agg<<<dim3(128, 8), 256, 0, stream>>>(adj, WhT1, sr1, dr1, num1, den1);
    // output projection
    k_out<<<128, 256, 0, stream>>>(num1, den1, Ow, Ob, (float*)d_out);
}

// Round 4
// 573.120 us; speedup vs baseline: 1.0173x; 1.0173x over previous
//
#include <hip/hip_runtime.h>

// ---------------------------------------------------------------------------
// GAT (2-layer) on MI355X. fp32 tensors, adj int32. N = 8192, D = 64.
//   k_prep0 : Wh0 = concat(ue,ie)@W0^T+b0 -> WhT0 (bf16) + s,d scalars.
//   k_agg<1,16> : layer-0 masked-softmax aggregation via MFMA 16x16x32 bf16.
//       Reads raw adj (256 MB), writes bitpacked adj (8 MB) as a side effect.
//       K split 16-way; per-split partial num/den written with PLAIN stores
//       (no atomics); consumer reduces.
//   k_prep1<16> : x1 = relu(sum(numP)/sum(denP)); Wh1 -> WhT1 + s,d.
//   k_agg<0,8>  : layer-1 aggregation reading the 8 MB bitmask only.
//   k_out<8>    : out = relu(sum(numP)/sum(denP)) @ out_w^T + out_b (fp32).
// Workspace ~43 MB. No atomics, no memsets.
// ---------------------------------------------------------------------------

typedef __attribute__((ext_vector_type(8))) __bf16 bf16x8;
typedef __attribute__((ext_vector_type(4))) float  f32x4;

union Frag {
    bf16x8         v;
    unsigned int   w[4];
    unsigned short h[8];
};

__device__ __forceinline__ unsigned short f2bf(float f) {
    unsigned int u = __float_as_uint(f);
    u += 0x7FFFu + ((u >> 16) & 1u);          // round-to-nearest-even
    return (unsigned short)(u >> 16);
}

// Shared GEMM tail: xs[64][65] holds x-tile, compute x@W^T+b, emit WhT + s,d.
__device__ __forceinline__ void prep_tail(
    float (*xs)[65], float (*Wt)[65], float (*sred)[64], float (*dred)[64],
    const float* __restrict__ W, const float* __restrict__ bias,
    const float* __restrict__ avec,
    unsigned short* __restrict__ WhT, float* __restrict__ sraw,
    float* __restrict__ draw, int tid, int r0)
{
    for (int e = tid; e < 4096; e += 256) {
        int o = e >> 6, c = e & 63;
        Wt[c][o] = W[e];                       // W[o][c] -> transposed LDS
    }
    __syncthreads();

    int r = tid & 63, chunk = tid >> 6, c0 = chunk * 16;
    float acc[16];
#pragma unroll
    for (int o = 0; o < 16; o++) acc[o] = bias[c0 + o];
    for (int c = 0; c < 64; c++) {
        float xv = xs[r][c];
#pragma unroll
        for (int o = 0; o < 16; o++) acc[o] += xv * Wt[c][c0 + o];
    }

    float sp = 0.f, dp = 0.f;
#pragma unroll
    for (int o = 0; o < 16; o++) {
        sp += acc[o] * avec[c0 + o];           // a[:64]
        dp += acc[o] * avec[64 + c0 + o];      // a[64:]
    }
    sred[chunk][r] = sp;
    dred[chunk][r] = dp;

#pragma unroll
    for (int o = 0; o < 16; o++)
        WhT[(c0 + o) * 8192 + r0 + r] = f2bf(acc[o]);

    __syncthreads();
    if (tid < 64) {
        int g = r0 + tid;
        sraw[g] = sred[0][tid] + sred[1][tid] + sred[2][tid] + sred[3][tid];
        draw[g] = dred[0][tid] + dred[1][tid] + dred[2][tid] + dred[3][tid];
    }
}

// ----------------------------- prep, layer 0 -------------------------------
__global__ __launch_bounds__(256) void k_prep0(
    const float* __restrict__ ue, const float* __restrict__ ie,
    const float* __restrict__ W, const float* __restrict__ bias,
    const float* __restrict__ avec,
    unsigned short* __restrict__ WhT,
    float* __restrict__ sraw, float* __restrict__ draw)
{
    __shared__ float xs[64][65];
    __shared__ float Wt[64][65];
    __shared__ float sred[4][64];
    __shared__ float dred[4][64];
    int tid = threadIdx.x, r0 = blockIdx.x * 64;

    for (int e = tid; e < 4096; e += 256) {
        int r = e >> 6, c = e & 63;
        int row = r0 + r;
        xs[r][c] = (row < 4096) ? ue[row * 64 + c] : ie[(row - 4096) * 64 + c];
    }
    prep_tail(xs, Wt, sred, dred, W, bias, avec, WhT, sraw, draw, tid, r0);
}

// ------------------- prep, layer 1 (reduces partials) ----------------------
template <int NS>
__global__ __launch_bounds__(256) void k_prep1(
    const float* __restrict__ numP, const float* __restrict__ denP,
    const float* __restrict__ W, const float* __restrict__ bias,
    const float* __restrict__ avec,
    unsigned short* __restrict__ WhT,
    float* __restrict__ sraw, float* __restrict__ draw)
{
    __shared__ float xs[64][65];
    __shared__ float Wt[64][65];
    __shared__ float sred[4][64];
    __shared__ float dred[4][64];
    __shared__ float dtot[64];
    int tid = threadIdx.x, r0 = blockIdx.x * 64;

    if (tid < 64) {
        float s = 0.f;
#pragma unroll
        for (int p = 0; p < NS; p++) s += denP[p * 8192 + r0 + tid];
        dtot[tid] = fmaxf(s, 1e-20f);
    }
    __syncthreads();
    for (int e = tid; e < 4096; e += 256) {
        int r = e >> 6, c = e & 63;
        float s = 0.f;
#pragma unroll
        for (int p = 0; p < NS; p++)
            s += numP[(size_t)p * 524288 + (r0 + r) * 64 + c];
        float v = s / dtot[r];
        xs[r][c] = v > 0.f ? v : 0.f;
    }
    prep_tail(xs, Wt, sred, dred, W, bias, avec, WhT, sraw, draw, tid, r0);
}

// --------------------------- aggregation (core) ----------------------------
// grid (128, NSPLIT). 4 waves/block, 16 rows/wave via mfma 16x16x32 bf16.
// A-frag: lane(l16,quad) holds A[m=l16][k=quad*8+j].
// C/D:    lane(l16,quad) holds D[row=quad*4+reg][col=l16].
// RAW=1: read raw adj, emit bitpacked mask. RAW=0: read bitmask only.
// Partials: plain stores to numP[ks] / denP[ks] — no atomics.
template <int RAW, int NSPLIT>
__global__ __launch_bounds__(256, 8) void k_agg(
    const int* __restrict__ adj, unsigned int* __restrict__ adjbits,
    const unsigned short* __restrict__ WhT,
    const float* __restrict__ sraw, const float* __restrict__ draw,
    float* __restrict__ numP, float* __restrict__ denP)
{
    const int KR = 8192 / NSPLIT;
    int tid  = threadIdx.x;
    int wave = tid >> 6, lane = tid & 63;
    int quad = lane >> 4, l16 = lane & 15;
    int rowblk = blockIdx.x, ks = blockIdx.y;
    int row = rowblk * 64 + wave * 16 + l16;
    int k0  = ks * KR;

    float sv = sraw[row];

    f32x4 accs[4];
    f32x4 accd = {0.f, 0.f, 0.f, 0.f};
#pragma unroll
    for (int nt = 0; nt < 4; nt++) accs[nt] = accd;

    Frag ones;
    ones.w[0] = ones.w[1] = ones.w[2] = ones.w[3] = 0x3F803F80u;  // bf16 1.0

    for (int kb = k0; kb < k0 + KR; kb += 32) {
        int kq = kb + quad * 8;                       // this lane's 8 k's

        unsigned int mask8;
        if constexpr (RAW) {
            const int4* ap = reinterpret_cast<const int4*>(adj + (size_t)row * 8192 + kq);
            int4 a0 = ap[0], a1 = ap[1];
            int ai[8] = {a0.x, a0.y, a0.z, a0.w, a1.x, a1.y, a1.z, a1.w};
            mask8 = 0;
#pragma unroll
            for (int j = 0; j < 8; j++)
                if (ai[j] != 0) mask8 |= (1u << j);
            reinterpret_cast<unsigned char*>(adjbits)[(size_t)row * 1024 + (kb >> 3) + quad] =
                (unsigned char)mask8;
        } else {
            unsigned int word = adjbits[row * 256 + (kb >> 5)];
            mask8 = (word >> (quad * 8)) & 0xFFu;
        }

        float4 dd0 = *reinterpret_cast<const float4*>(draw + kq);
        float4 dd1 = *reinterpret_cast<const float4*>(draw + kq + 4);
        float dv[8] = {dd0.x, dd0.y, dd0.z, dd0.w, dd1.x, dd1.y, dd1.z, dd1.w};

        Frag A;
#pragma unroll
        for (int j = 0; j < 8; j++) {
            float t  = sv + dv[j];
            float lr = t > 0.f ? t : 0.2f * t;        // leaky_relu, alpha=0.2
            float w  = ((mask8 >> j) & 1u) ? __expf(lr) : 0.f;
            A.h[j] = f2bf(w);
        }

#pragma unroll
        for (int nt = 0; nt < 4; nt++) {
            Frag B;
            B.v = *reinterpret_cast<const bf16x8*>(WhT + (size_t)(nt * 16 + l16) * 8192 + kq);
            accs[nt] = __builtin_amdgcn_mfma_f32_16x16x32_bf16(A.v, B.v, accs[nt], 0, 0, 0);
        }
        accd = __builtin_amdgcn_mfma_f32_16x16x32_bf16(A.v, ones.v, accd, 0, 0, 0);
    }

    int rbase = rowblk * 64 + wave * 16 + quad * 4;
    size_t nb = (size_t)ks * 524288;
#pragma unroll
    for (int rr = 0; rr < 4; rr++) {
        if (l16 == 0) denP[ks * 8192 + rbase + rr] = accd[rr];
#pragma unroll
        for (int nt = 0; nt < 4; nt++)
            numP[nb + (size_t)(rbase + rr) * 64 + nt * 16 + l16] = accs[nt][rr];
    }
}

// ----------------------------- output GEMM ---------------------------------
template <int NS>
__global__ __launch_bounds__(256) void k_out(
    const float* __restrict__ numP, const float* __restrict__ denP,
    const float* __restrict__ W, const float* __restrict__ bias,
    float* __restrict__ out)
{
    __shared__ float xs[64][65];
    __shared__ float Wt[64][65];
    __shared__ float dtot[64];
    int tid = threadIdx.x, r0 = blockIdx.x * 64;

    if (tid < 64) {
        float s = 0.f;
#pragma unroll
        for (int p = 0; p < NS; p++) s += denP[p * 8192 + r0 + tid];
        dtot[tid] = fmaxf(s, 1e-20f);
    }
    __syncthreads();
    for (int e = tid; e < 4096; e += 256) {
        int r = e >> 6, c = e & 63;
        float s = 0.f;
#pragma unroll
        for (int p = 0; p < NS; p++)
            s += numP[(size_t)p * 524288 + (r0 + r) * 64 + c];
        float v = s / dtot[r];
        xs[r][c] = v > 0.f ? v : 0.f;
    }
    for (int e = tid; e < 4096; e += 256) {
        int o = e >> 6, c = e & 63;
        Wt[c][o] = W[e];
    }
    __syncthreads();

    int r = tid & 63, chunk = tid >> 6, c0 = chunk * 16;
    float acc[16];
#pragma unroll
    for (int o = 0; o < 16; o++) acc[o] = bias[c0 + o];
    for (int c = 0; c < 64; c++) {
        float xv = xs[r][c];
#pragma unroll
        for (int o = 0; o < 16; o++) acc[o] += xv * Wt[c][c0 + o];
    }
#pragma unroll
    for (int o = 0; o < 16; o++)
        out[(r0 + r) * 64 + c0 + o] = acc[o];
}

// ------------------------------- launch ------------------------------------
extern "C" void kernel_launch(void* const* d_in, const int* in_sizes, int n_in,
                              void* d_out, int out_size, void* d_ws, size_t ws_size,
                              hipStream_t stream)
{
    const int*   adj = (const int*)d_in[0];
    const float* ue  = (const float*)d_in[1];
    const float* ie  = (const float*)d_in[2];
    const float* W0w = (const float*)d_in[3];
    const float* W0b = (const float*)d_in[4];
    const float* a0  = (const float*)d_in[5];
    const float* W1w = (const float*)d_in[6];
    const float* W1b = (const float*)d_in[7];
    const float* a1  = (const float*)d_in[8];
    const float* Ow  = (const float*)d_in[9];
    const float* Ob  = (const float*)d_in[10];

    constexpr int NS0 = 16, NS1 = 8;

    char* ws = (char*)d_ws;
    size_t off = 0;
    auto alloc = [&](size_t bytes) -> char* {
        char* p = ws + off;
        off += (bytes + 255) & ~(size_t)255;
        return p;
    };
    float*          numP    = (float*)alloc((size_t)NS0 * 524288 * 4);  // 32 MB
    float*          denP    = (float*)alloc((size_t)NS0 * 8192 * 4);    // 512 KB
    unsigned int*   adjbits = (unsigned int*)alloc(8192 * 1024);        // 8 MB
    unsigned short* WhT0    = (unsigned short*)alloc(64 * 8192 * 2);    // 1 MB
    unsigned short* WhT1    = (unsigned short*)alloc(64 * 8192 * 2);    // 1 MB
    float* sr0 = (float*)alloc(8192 * 4);
    float* dr0 = (float*)alloc(8192 * 4);
    float* sr1 = (float*)alloc(8192 * 4);
    float* dr1 = (float*)alloc(8192 * 4);
    // total ~43 MB; partial buffers are fully overwritten each launch, so no
    // zeroing is needed (0xAA ws poison is harmless).

    // layer 0 (reads raw adj, emits bitpacked adj)
    k_prep0<<<128, 256, 0, stream>>>(ue, ie, W0w, W0b, a0, WhT0, sr0, dr0);
    k_agg<1, NS0><<<dim3(128, NS0), 256, 0, stream>>>(adj, adjbits, WhT0,
                                                      sr0, dr0, numP, denP);
    // layer 1 (reads bitpacked adj; reuses the partial buffers)
    k_prep1<NS0><<<128, 256, 0, stream>>>(numP, denP, W1w, W1b, a1, WhT1, sr1, dr1);
    k_agg<0, NS1><<<dim3(128, NS1), 256, 0, stream>>>((const int*)nullptr, adjbits, WhT1,
                                                      sr1, dr1, numP, denP);
    // output projection
    k_out<NS1><<<128, 256, 0, stream>>>(numP, denP, Ow, Ob, (float*)d_out);
}